// Round 1
// baseline (446.871 us; speedup 1.0000x reference)
//
#include <hip/hip_runtime.h>
#include <hip/hip_bf16.h>
#include <cstdint>

#define BB 64
#define NN_ 500
#define NP 512
#define EE 128
#define NHEAD 8
#define HD 16

typedef float f32x4 __attribute__((ext_vector_type(4)));
typedef short s16x8 __attribute__((ext_vector_type(8)));
typedef short s16x4 __attribute__((ext_vector_type(4)));

__device__ __forceinline__ unsigned short f2bf(float f) {
  unsigned u = __builtin_bit_cast(unsigned, f);
  u += 0x7FFFu + ((u >> 16) & 1u);
  return (unsigned short)(u >> 16);
}

__device__ __forceinline__ f32x4 MFMA(s16x8 a, s16x8 b, f32x4 c) {
  return __builtin_amdgcn_mfma_f32_16x16x32_bf16(a, b, c, 0, 0, 0);
}

// ---------------- K0a: ef fp32 -> bf16, padded rows 500..511 = 0 ----------------
__global__ void k_conv_ef(const float* __restrict__ ef, unsigned short* __restrict__ out) {
  int idx = blockIdx.x * 256 + threadIdx.x;   // B*NP*16 = 524288
  int e8 = idx & 15;
  int n  = (idx >> 4) & (NP - 1);
  int b  = idx >> 13;
  s16x8 o = {0,0,0,0,0,0,0,0};
  if (n < NN_) {
    const float* p = ef + ((size_t)(b * NN_ + n)) * EE + e8 * 8;
    float4 f0 = *reinterpret_cast<const float4*>(p);
    float4 f1 = *reinterpret_cast<const float4*>(p + 4);
    o[0]=(short)f2bf(f0.x); o[1]=(short)f2bf(f0.y); o[2]=(short)f2bf(f0.z); o[3]=(short)f2bf(f0.w);
    o[4]=(short)f2bf(f1.x); o[5]=(short)f2bf(f1.y); o[6]=(short)f2bf(f1.z); o[7]=(short)f2bf(f1.w);
  }
  *reinterpret_cast<s16x8*>(out + ((size_t)(b * NP + n)) * EE + e8 * 8) = o;
}

// ---------------- K0b: W^T bf16; mats order [q1,q0,k,v,c], WT[m][n][k]=W[k][n] ----------------
__global__ void k_conv_w(const float* __restrict__ w0, const float* __restrict__ w1,
                         const float* __restrict__ w2, const float* __restrict__ w3,
                         const float* __restrict__ w4, unsigned short* __restrict__ wt) {
  int idx = blockIdx.x * 256 + threadIdx.x;   // 5*128*128 = 81920
  int k = idx & 127;
  int n = (idx >> 7) & 127;
  int m = idx >> 14;
  const float* w = (m == 0) ? w0 : (m == 1) ? w1 : (m == 2) ? w2 : (m == 3) ? w3 : w4;
  wt[idx] = f2bf(w[k * 128 + n]);
}

// ---------------- K1: projections -> Q_bf, K_bf (row-major), VT_bf (d-major) ----------------
__global__ __launch_bounds__(256) void k_proj(
    const unsigned short* __restrict__ ef_bf,
    const float* __restrict__ eq1, const float* __restrict__ eq0,
    const unsigned short* __restrict__ wt,
    unsigned short* __restrict__ q_bf, unsigned short* __restrict__ k_bf,
    unsigned short* __restrict__ vt_bf) {
  int wgid = blockIdx.x;                 // 1024
  int b = wgid >> 4, nt = wgid & 15;
  int tid = threadIdx.x;
  int w = tid >> 6, lane = tid & 63, g = lane >> 4, c = lane & 15;
  int rw = w & 1, cw = w >> 1;
  int nbase = nt * 32 + rw * 16;

  f32x4 ak[4], av[4], aq[4];
#pragma unroll
  for (int t = 0; t < 4; ++t) { ak[t]=(f32x4){0,0,0,0}; av[t]=(f32x4){0,0,0,0}; aq[t]=(f32x4){0,0,0,0}; }

  int nA = nbase + c;
  int nc = nA < NN_ ? nA : NN_ - 1;

  for (int kk = 0; kk < 4; ++kk) {
    int k0 = kk * 32 + 8 * g;
    s16x8 aef = *reinterpret_cast<const s16x8*>(ef_bf + ((size_t)(b * NP + nA)) * EE + k0);
    const float* p1 = eq1 + ((size_t)(b * NN_ + nc)) * EE + k0;
    const float* p0 = eq0 + ((size_t)(b * NN_ + nc)) * EE + k0;
    float4 u1 = *reinterpret_cast<const float4*>(p1);
    float4 u2 = *reinterpret_cast<const float4*>(p1 + 4);
    float4 v1 = *reinterpret_cast<const float4*>(p0);
    float4 v2 = *reinterpret_cast<const float4*>(p0 + 4);
    s16x8 a1, a0;
    a1[0]=(short)f2bf(u1.x); a1[1]=(short)f2bf(u1.y); a1[2]=(short)f2bf(u1.z); a1[3]=(short)f2bf(u1.w);
    a1[4]=(short)f2bf(u2.x); a1[5]=(short)f2bf(u2.y); a1[6]=(short)f2bf(u2.z); a1[7]=(short)f2bf(u2.w);
    a0[0]=(short)f2bf(v1.x); a0[1]=(short)f2bf(v1.y); a0[2]=(short)f2bf(v1.z); a0[3]=(short)f2bf(v1.w);
    a0[4]=(short)f2bf(v2.x); a0[5]=(short)f2bf(v2.y); a0[6]=(short)f2bf(v2.z); a0[7]=(short)f2bf(v2.w);
#pragma unroll
    for (int tc = 0; tc < 4; ++tc) {
      int e = cw * 64 + tc * 16 + c;
      const unsigned short* wrow = wt + e * EE + k0;
      s16x8 bq1 = *reinterpret_cast<const s16x8*>(wrow);
      s16x8 bq0 = *reinterpret_cast<const s16x8*>(wrow + 1 * 16384);
      s16x8 bk  = *reinterpret_cast<const s16x8*>(wrow + 2 * 16384);
      s16x8 bv  = *reinterpret_cast<const s16x8*>(wrow + 3 * 16384);
      ak[tc] = MFMA(aef, bk, ak[tc]);
      av[tc] = MFMA(aef, bv, av[tc]);
      aq[tc] = MFMA(a1, bq1, aq[tc]);
      aq[tc] = MFMA(a0, bq0, aq[tc]);
    }
  }
#pragma unroll
  for (int tc = 0; tc < 4; ++tc) {
    int e = cw * 64 + tc * 16 + c;
    int h = e >> 4, d = e & 15;
    s16x4 pv4;
#pragma unroll
    for (int r = 0; r < 4; ++r) {
      int n = nbase + 4 * g + r;
      bool val = (n < NN_);
      size_t off = ((size_t)(b * NP + n)) * EE + e;
      k_bf[off] = val ? f2bf(ak[tc][r]) : 0;
      q_bf[off] = val ? f2bf(aq[tc][r]) : 0;
      pv4[r] = val ? (short)f2bf(av[tc][r]) : (short)0;
    }
    int n0 = nbase + 4 * g;
    *reinterpret_cast<s16x4*>(vt_bf + (((size_t)(b * NHEAD + h)) * HD + d) * NP + n0) = pv4;
  }
}

// ---------------- K2: fused attention per (b, h, 32-row n-tile) ----------------
// Swapped orientation: S^T = mfma(K, Q) so lane&15 = n; softmax over m is lane-local+shfl.
__global__ __launch_bounds__(256) void k_attn(
    const unsigned short* __restrict__ q_bf, const unsigned short* __restrict__ k_bf,
    const unsigned short* __restrict__ vt_bf, const float* __restrict__ mask,
    unsigned short* __restrict__ ao_bf) {
  int wgid = blockIdx.x;                 // 8192
  int xcd = wgid & 7;
  int s = wgid >> 3;
  int h = s & 7;
  int gq = s >> 3;                       // 0..127
  int grp = gq * 8 + xcd;                // 0..1023 : all 8 h of a group on same XCD
  int b = grp >> 4, nt = grp & 15;
  int tid = threadIdx.x, w = tid >> 6, lane = tid & 63, g = lane >> 4, c = lane & 15;
  int mw = w & 1, nw = w >> 1;
  int n = nt * 32 + nw * 16 + c;         // this lane's n for all its values

  // Q fragment (B operand, col = n on lane&15), K slots 0..3 = d(4g..4g+3), 4..7 zero
  s16x8 bq = {0,0,0,0,0,0,0,0};
  {
    s16x4 t4 = *reinterpret_cast<const s16x4*>(q_bf + ((size_t)(b * NP + n)) * EE + h * HD + 4 * g);
    bq[0]=t4[0]; bq[1]=t4[1]; bq[2]=t4[2]; bq[3]=t4[3];
  }
  f32x4 acc[16];
#pragma unroll
  for (int t = 0; t < 16; ++t) {
    int mbase = mw * 256 + t * 16;
    s16x8 akf = {0,0,0,0,0,0,0,0};
    s16x4 t4 = *reinterpret_cast<const s16x4*>(k_bf + ((size_t)(b * NP + mbase + c)) * EE + h * HD + 4 * g);
    akf[0]=t4[0]; akf[1]=t4[1]; akf[2]=t4[2]; akf[3]=t4[3];
    acc[t] = MFMA(akf, bq, (f32x4){0,0,0,0});
  }
  // logits = score*0.25 + mask ; invalid m -> -3e38
  bool nvalid = (n < NN_);
  float lmax = -3e38f;
#pragma unroll
  for (int t = 0; t < 16; ++t) {
    int mb = mw * 256 + t * 16 + 4 * g;
#pragma unroll
    for (int r = 0; r < 4; ++r) {
      int m = mb + r;
      float lv;
      if (m < NN_) {
        float mv = nvalid ? mask[((size_t)b * NN_ + n) * NN_ + m] : 0.0f;
        lv = acc[t][r] * 0.25f + mv;
      } else {
        lv = -3e38f;
      }
      acc[t][r] = lv;
      lmax = fmaxf(lmax, lv);
    }
  }
  lmax = fmaxf(lmax, __shfl_xor(lmax, 16));
  lmax = fmaxf(lmax, __shfl_xor(lmax, 32));
  __shared__ float redmax[2][2][16];
  __shared__ float redsum[2][2][16];
  __shared__ float pvred[2][2][16][16];
  if (g == 0) redmax[mw][nw][c] = lmax;
  __syncthreads();
  float gmax = fmaxf(redmax[0][nw][c], redmax[1][nw][c]);
  float lsum = 0.0f;
#pragma unroll
  for (int t = 0; t < 16; ++t) {
#pragma unroll
    for (int r = 0; r < 4; ++r) {
      float p = exp2f((acc[t][r] - gmax) * 1.4426950408889634f);
      acc[t][r] = p;
      lsum += p;
    }
  }
  lsum += __shfl_xor(lsum, 16);
  lsum += __shfl_xor(lsum, 32);
  if (g == 0) redsum[mw][nw][c] = lsum;
  __syncthreads();
  float gsum = redsum[0][nw][c] + redsum[1][nw][c];

  // PV: out^T = V^T * P ; A slots (g,j): m = m0 + 16*(j>>2) + 4g + (j&3); B same placement
  const unsigned short* vrow = vt_bf + (((size_t)(b * NHEAD + h)) * HD + c) * NP;
  f32x4 o = {0,0,0,0};
#pragma unroll
  for (int T = 0; T < 8; ++T) {
    int m0 = mw * 256 + T * 32;
    s16x4 va = *reinterpret_cast<const s16x4*>(vrow + m0 + 4 * g);
    s16x4 vb = *reinterpret_cast<const s16x4*>(vrow + m0 + 16 + 4 * g);
    s16x8 af = { va[0], va[1], va[2], va[3], vb[0], vb[1], vb[2], vb[3] };
    s16x8 bf;
#pragma unroll
    for (int j = 0; j < 4; ++j) {
      bf[j]     = (short)f2bf(acc[2 * T][j]);
      bf[j + 4] = (short)f2bf(acc[2 * T + 1][j]);
    }
    o = MFMA(af, bf, o);
  }
#pragma unroll
  for (int r = 0; r < 4; ++r) pvred[mw][nw][4 * g + r][c] = o[r];
  __syncthreads();
  if (mw == 0) {
    float inv = 1.0f / gsum;
    int d0 = 4 * g;
    s16x4 st;
#pragma unroll
    for (int r = 0; r < 4; ++r) {
      float v = (pvred[0][nw][d0 + r][c] + pvred[1][nw][d0 + r][c]) * inv;
      st[r] = (short)f2bf(v);
    }
    *reinterpret_cast<s16x4*>(ao_bf + ((size_t)(b * NP + n)) * EE + h * HD + d0) = st;
  }
}

// ---------------- K3: mh = attn_out @ Wc + bc -> bf16 ----------------
__global__ __launch_bounds__(256) void k_comb(
    const unsigned short* __restrict__ ao_bf, const unsigned short* __restrict__ wt,
    const float* __restrict__ bc, unsigned short* __restrict__ mh_bf) {
  int wgid = blockIdx.x;                 // 1024
  int b = wgid >> 4, nt = wgid & 15;
  int tid = threadIdx.x;
  int w = tid >> 6, lane = tid & 63, g = lane >> 4, c = lane & 15;
  int rw = w & 1, cw = w >> 1;
  int nbase = nt * 32 + rw * 16;
  int nA = nbase + c;
  f32x4 a4[4];
#pragma unroll
  for (int t = 0; t < 4; ++t) a4[t] = (f32x4){0,0,0,0};
  for (int kk = 0; kk < 4; ++kk) {
    int k0 = kk * 32 + 8 * g;
    s16x8 aa = *reinterpret_cast<const s16x8*>(ao_bf + ((size_t)(b * NP + nA)) * EE + k0);
#pragma unroll
    for (int tc = 0; tc < 4; ++tc) {
      int e = cw * 64 + tc * 16 + c;
      s16x8 bw = *reinterpret_cast<const s16x8*>(wt + 4 * 16384 + e * EE + k0);
      a4[tc] = MFMA(aa, bw, a4[tc]);
    }
  }
#pragma unroll
  for (int tc = 0; tc < 4; ++tc) {
    int e = cw * 64 + tc * 16 + c;
    float bias = bc[e];
#pragma unroll
    for (int r = 0; r < 4; ++r) {
      int n = nbase + 4 * g + r;
      mh_bf[((size_t)(b * NP + n)) * EE + e] = f2bf(a4[tc][r] + bias);
    }
  }
}

// ---------------- K4: pointer attention: s = mh@ef^T /sqrt(128); 10*tanh + mask; softmax ----------------
__global__ __launch_bounds__(256) void k_logits(
    const unsigned short* __restrict__ mh_bf, const unsigned short* __restrict__ ef_bf,
    const float* __restrict__ mask, float* __restrict__ probs) {
  int wgid = blockIdx.x;                 // 1024
  int xcd = wgid & 7;
  int sfl = wgid >> 3;
  int nt = sfl & 15;
  int bq = sfl >> 4;                     // 0..7
  int b = bq * 8 + xcd;                  // same-b tiles on same XCD
  int tid = threadIdx.x, w = tid >> 6, lane = tid & 63, g = lane >> 4, c = lane & 15;
  int rw = w & 1, cw = w >> 1;
  int nbase = nt * 32 + rw * 16;
  int nA = nbase + c;

  f32x4 acc[16];
#pragma unroll
  for (int t = 0; t < 16; ++t) acc[t] = (f32x4){0,0,0,0};
  for (int kk = 0; kk < 4; ++kk) {
    int k0 = kk * 32 + 8 * g;
    s16x8 af = *reinterpret_cast<const s16x8*>(mh_bf + ((size_t)(b * NP + nA)) * EE + k0);
#pragma unroll
    for (int t = 0; t < 16; ++t) {
      int m = cw * 256 + t * 16 + c;
      s16x8 bfr = *reinterpret_cast<const s16x8*>(ef_bf + ((size_t)(b * NP + m)) * EE + k0);
      acc[t] = MFMA(af, bfr, acc[t]);
    }
  }
  float rmax[4] = {-3e38f, -3e38f, -3e38f, -3e38f};
#pragma unroll
  for (int t = 0; t < 16; ++t) {
    int m = cw * 256 + t * 16 + c;
#pragma unroll
    for (int r = 0; r < 4; ++r) {
      int n = nbase + 4 * g + r;
      float lv;
      if (m < NN_) {
        float x = acc[t][r] * 0.08838834764831845f;  // 1/sqrt(128)
        float ax = fabsf(x);
        float e2 = exp2f(ax * 2.8853900817779268f);  // e^(2|x|)
        float th = copysignf(1.0f - 2.0f / (e2 + 1.0f), x);
        float mv = (n < NN_) ? mask[((size_t)b * NN_ + n) * NN_ + m] : 0.0f;
        lv = 10.0f * th + mv;
      } else {
        lv = -3e38f;
      }
      acc[t][r] = lv;
      rmax[r] = fmaxf(rmax[r], lv);
    }
  }
#pragma unroll
  for (int r = 0; r < 4; ++r) {
    rmax[r] = fmaxf(rmax[r], __shfl_xor(rmax[r], 1));
    rmax[r] = fmaxf(rmax[r], __shfl_xor(rmax[r], 2));
    rmax[r] = fmaxf(rmax[r], __shfl_xor(rmax[r], 4));
    rmax[r] = fmaxf(rmax[r], __shfl_xor(rmax[r], 8));
  }
  __shared__ float redm[2][32];
  __shared__ float reds[2][32];
  int rowid = rw * 16 + 4 * g;
  if (c == 0) {
#pragma unroll
    for (int r = 0; r < 4; ++r) redm[cw][rowid + r] = rmax[r];
  }
  __syncthreads();
  float gmax[4];
#pragma unroll
  for (int r = 0; r < 4; ++r) gmax[r] = fmaxf(redm[0][rowid + r], redm[1][rowid + r]);
  float rsum[4] = {0, 0, 0, 0};
#pragma unroll
  for (int t = 0; t < 16; ++t) {
#pragma unroll
    for (int r = 0; r < 4; ++r) {
      float p = exp2f((acc[t][r] - gmax[r]) * 1.4426950408889634f);
      acc[t][r] = p;
      rsum[r] += p;
    }
  }
#pragma unroll
  for (int r = 0; r < 4; ++r) {
    rsum[r] += __shfl_xor(rsum[r], 1);
    rsum[r] += __shfl_xor(rsum[r], 2);
    rsum[r] += __shfl_xor(rsum[r], 4);
    rsum[r] += __shfl_xor(rsum[r], 8);
  }
  if (c == 0) {
#pragma unroll
    for (int r = 0; r < 4; ++r) reds[cw][rowid + r] = rsum[r];
  }
  __syncthreads();
  float inv[4];
#pragma unroll
  for (int r = 0; r < 4; ++r) inv[r] = 1.0f / (reds[0][rowid + r] + reds[1][rowid + r]);
#pragma unroll
  for (int t = 0; t < 16; ++t) {
    int m = cw * 256 + t * 16 + c;
    if (m < NN_) {
#pragma unroll
      for (int r = 0; r < 4; ++r) {
        int n = nbase + 4 * g + r;
        if (n < NN_) probs[((size_t)b * NN_ + n) * NN_ + m] = acc[t][r] * inv[r];
      }
    }
  }
}

extern "C" void kernel_launch(void* const* d_in, const int* in_sizes, int n_in,
                              void* d_out, int out_size, void* d_ws, size_t ws_size,
                              hipStream_t stream) {
  const float* ef   = (const float*)d_in[0];
  const float* eq1  = (const float*)d_in[1];
  const float* eq0  = (const float*)d_in[2];
  const float* mask = (const float*)d_in[3];
  const float* wq1  = (const float*)d_in[4];
  const float* wq0  = (const float*)d_in[5];
  const float* wk   = (const float*)d_in[6];
  const float* wv   = (const float*)d_in[7];
  const float* wc   = (const float*)d_in[8];
  const float* bc   = (const float*)d_in[9];
  float* probs = (float*)d_out;

  char* ws = (char*)d_ws;
  const size_t SL = 8388608;  // 64*512*128*2 bytes
  unsigned short* ef_bf = (unsigned short*)(ws);
  unsigned short* q_bf  = (unsigned short*)(ws + 1 * SL);
  unsigned short* k_bf  = (unsigned short*)(ws + 2 * SL);
  unsigned short* vt_bf = (unsigned short*)(ws + 3 * SL);
  unsigned short* ao_bf = (unsigned short*)(ws + 4 * SL);
  unsigned short* mh_bf = (unsigned short*)(ws + 5 * SL);
  unsigned short* wt    = (unsigned short*)(ws + 6 * SL);

  k_conv_ef<<<2048, 256, 0, stream>>>(ef, ef_bf);
  k_conv_w<<<320, 256, 0, stream>>>(wq1, wq0, wk, wv, wc, wt);
  k_proj<<<1024, 256, 0, stream>>>(ef_bf, eq1, eq0, wt, q_bf, k_bf, vt_bf);
  k_attn<<<8192, 256, 0, stream>>>(q_bf, k_bf, vt_bf, mask, ao_bf);
  k_comb<<<1024, 256, 0, stream>>>(ao_bf, wt, bc, mh_bf);
  k_logits<<<1024, 256, 0, stream>>>(mh_bf, ef_bf, mask, probs);
}

// Round 2
// 322.035 us; speedup vs baseline: 1.3876x; 1.3876x over previous
//
#include <hip/hip_runtime.h>
#include <hip/hip_bf16.h>
#include <cstdint>

#define BB 64
#define NN_ 500
#define NP 512
#define EE 128
#define NHEAD 8
#define HD 16

typedef float f32x4 __attribute__((ext_vector_type(4)));
typedef short s16x8 __attribute__((ext_vector_type(8)));
typedef short s16x4 __attribute__((ext_vector_type(4)));

__device__ __forceinline__ unsigned short f2bf(float f) {
  unsigned u = __builtin_bit_cast(unsigned, f);
  u += 0x7FFFu + ((u >> 16) & 1u);
  return (unsigned short)(u >> 16);
}

__device__ __forceinline__ f32x4 MFMA(s16x8 a, s16x8 b, f32x4 c) {
  return __builtin_amdgcn_mfma_f32_16x16x32_bf16(a, b, c, 0, 0, 0);
}

// ---------------- K0a: ef fp32 -> bf16, padded rows 500..511 = 0 ----------------
__global__ void k_conv_ef(const float* __restrict__ ef, unsigned short* __restrict__ out) {
  int idx = blockIdx.x * 256 + threadIdx.x;   // B*NP*16 = 524288
  int e8 = idx & 15;
  int n  = (idx >> 4) & (NP - 1);
  int b  = idx >> 13;
  s16x8 o = {0,0,0,0,0,0,0,0};
  if (n < NN_) {
    const float* p = ef + ((size_t)(b * NN_ + n)) * EE + e8 * 8;
    float4 f0 = *reinterpret_cast<const float4*>(p);
    float4 f1 = *reinterpret_cast<const float4*>(p + 4);
    o[0]=(short)f2bf(f0.x); o[1]=(short)f2bf(f0.y); o[2]=(short)f2bf(f0.z); o[3]=(short)f2bf(f0.w);
    o[4]=(short)f2bf(f1.x); o[5]=(short)f2bf(f1.y); o[6]=(short)f2bf(f1.z); o[7]=(short)f2bf(f1.w);
  }
  *reinterpret_cast<s16x8*>(out + ((size_t)(b * NP + n)) * EE + e8 * 8) = o;
}

// ---------------- K0b: W^T bf16; mats order [q1,q0,k,v,c], WT[m][n][k]=W[k][n] ----------------
__global__ void k_conv_w(const float* __restrict__ w0, const float* __restrict__ w1,
                         const float* __restrict__ w2, const float* __restrict__ w3,
                         const float* __restrict__ w4, unsigned short* __restrict__ wt) {
  int idx = blockIdx.x * 256 + threadIdx.x;   // 5*128*128 = 81920
  int k = idx & 127;
  int n = (idx >> 7) & 127;
  int m = idx >> 14;
  const float* w = (m == 0) ? w0 : (m == 1) ? w1 : (m == 2) ? w2 : (m == 3) ? w3 : w4;
  wt[idx] = f2bf(w[k * 128 + n]);
}

// ---------------- K1: projections -> QH, KH head-major [b][h][n][16], VT [b][h][16][n] ----------------
__global__ __launch_bounds__(256) void k_proj(
    const unsigned short* __restrict__ ef_bf,
    const float* __restrict__ eq1, const float* __restrict__ eq0,
    const unsigned short* __restrict__ wt,
    unsigned short* __restrict__ qh, unsigned short* __restrict__ kh,
    unsigned short* __restrict__ vt_bf) {
  int wgid = blockIdx.x;                 // 1024
  int xcd = wgid & 7;
  int s = wgid >> 3;
  int nt = s & 15;
  int b = (s >> 4) * 8 + xcd;
  int tid = threadIdx.x;
  int w = tid >> 6, lane = tid & 63, g = lane >> 4, c = lane & 15;
  int rw = w & 1, cw = w >> 1;
  int nbase = nt * 32 + rw * 16;

  f32x4 ak[4], av[4], aq[4];
#pragma unroll
  for (int t = 0; t < 4; ++t) { ak[t]=(f32x4){0,0,0,0}; av[t]=(f32x4){0,0,0,0}; aq[t]=(f32x4){0,0,0,0}; }

  int nA = nbase + c;
  int nc = nA < NN_ ? nA : NN_ - 1;

  for (int kk = 0; kk < 4; ++kk) {
    int k0 = kk * 32 + 8 * g;
    s16x8 aef = *reinterpret_cast<const s16x8*>(ef_bf + ((size_t)(b * NP + nA)) * EE + k0);
    const float* p1 = eq1 + ((size_t)(b * NN_ + nc)) * EE + k0;
    const float* p0 = eq0 + ((size_t)(b * NN_ + nc)) * EE + k0;
    float4 u1 = *reinterpret_cast<const float4*>(p1);
    float4 u2 = *reinterpret_cast<const float4*>(p1 + 4);
    float4 v1 = *reinterpret_cast<const float4*>(p0);
    float4 v2 = *reinterpret_cast<const float4*>(p0 + 4);
    s16x8 a1, a0;
    a1[0]=(short)f2bf(u1.x); a1[1]=(short)f2bf(u1.y); a1[2]=(short)f2bf(u1.z); a1[3]=(short)f2bf(u1.w);
    a1[4]=(short)f2bf(u2.x); a1[5]=(short)f2bf(u2.y); a1[6]=(short)f2bf(u2.z); a1[7]=(short)f2bf(u2.w);
    a0[0]=(short)f2bf(v1.x); a0[1]=(short)f2bf(v1.y); a0[2]=(short)f2bf(v1.z); a0[3]=(short)f2bf(v1.w);
    a0[4]=(short)f2bf(v2.x); a0[5]=(short)f2bf(v2.y); a0[6]=(short)f2bf(v2.z); a0[7]=(short)f2bf(v2.w);
#pragma unroll
    for (int tc = 0; tc < 4; ++tc) {
      int e = cw * 64 + tc * 16 + c;
      const unsigned short* wrow = wt + e * EE + k0;
      s16x8 bq1 = *reinterpret_cast<const s16x8*>(wrow);
      s16x8 bq0 = *reinterpret_cast<const s16x8*>(wrow + 1 * 16384);
      s16x8 bk  = *reinterpret_cast<const s16x8*>(wrow + 2 * 16384);
      s16x8 bv  = *reinterpret_cast<const s16x8*>(wrow + 3 * 16384);
      ak[tc] = MFMA(aef, bk, ak[tc]);
      av[tc] = MFMA(aef, bv, av[tc]);
      aq[tc] = MFMA(a1, bq1, aq[tc]);
      aq[tc] = MFMA(a0, bq0, aq[tc]);
    }
  }
#pragma unroll
  for (int tc = 0; tc < 4; ++tc) {
    int h = cw * 4 + tc;                 // e = cw*64+tc*16+c -> head, d = c
    s16x4 pv4;
#pragma unroll
    for (int r = 0; r < 4; ++r) {
      int n = nbase + 4 * g + r;
      bool val = (n < NN_);
      size_t off = ((size_t)((b * NHEAD + h) * NP) + n) * HD + c;
      kh[off] = val ? f2bf(ak[tc][r]) : 0;
      qh[off] = val ? f2bf(aq[tc][r]) : 0;
      pv4[r] = val ? (short)f2bf(av[tc][r]) : (short)0;
    }
    int n0 = nbase + 4 * g;
    *reinterpret_cast<s16x4*>(vt_bf + (((size_t)(b * NHEAD + h)) * HD + c) * NP + n0) = pv4;
  }
}

// ---------------- K2: fused attention per (b, 32-row n-tile), 8-head inner loop ----------------
// Swapped orientation: S^T = mfma(K, Q) so lane&15 = n; softmax over m is lane-local+shfl.
// Mask tile staged once (coalesced) -> LDS -> 64 registers, reused across all 8 heads.
__global__ __launch_bounds__(256) void k_attn(
    const unsigned short* __restrict__ qh, const unsigned short* __restrict__ kh,
    const unsigned short* __restrict__ vt, const float* __restrict__ mask,
    unsigned short* __restrict__ ao_bf) {
  int wgid = blockIdx.x;                 // 1024
  int xcd = wgid & 7;
  int s = wgid >> 3;
  int nt = s & 15;
  int b = (s >> 4) * 8 + xcd;            // all 16 tiles of b on one XCD
  int tid = threadIdx.x, w = tid >> 6, lane = tid & 63, g = lane >> 4, c = lane & 15;
  int mw = w & 1, nw = w >> 1;
  int nt32 = nt * 32;
  int nl = nw * 16 + c;
  int n = nt32 + nl;

  __shared__ float smask[32][516];       // 66048 B, padded stride (516%32==4 -> 2-way max, free)
  __shared__ float redmax[2][2][16];
  __shared__ float redsum[2][2][16];
  __shared__ float pvred[2][2][16][17];  // padded to kill 4-way conflict

  // zero pad cols 500..515 (keep everything finite)
  for (int idx = tid; idx < 32 * 16; idx += 256)
    smask[idx >> 4][500 + (idx & 15)] = 0.0f;
  // stage mask tile, coalesced float4; zero rows for n>=500
  for (int idx = tid; idx < 32 * 125; idx += 256) {
    int rl = idx / 125;
    int m4 = idx - rl * 125;
    int nr = nt32 + rl;
    float4 v = {0.0f, 0.0f, 0.0f, 0.0f};
    if (nr < NN_) v = *reinterpret_cast<const float4*>(mask + ((size_t)b * NN_ + nr) * NN_ + m4 * 4);
    *reinterpret_cast<float4*>(&smask[rl][m4 * 4]) = v;
  }
  __syncthreads();

  // pull this lane's 64 mask values into registers once
  f32x4 mreg[16];
#pragma unroll
  for (int t = 0; t < 16; ++t)
    mreg[t] = *reinterpret_cast<const f32x4*>(&smask[nl][mw * 256 + t * 16 + 4 * g]);

  for (int h = 0; h < NHEAD; ++h) {
    const unsigned short* qb = qh + ((size_t)(b * NHEAD + h)) * NP * HD;
    const unsigned short* kb = kh + ((size_t)(b * NHEAD + h)) * NP * HD;
    const unsigned short* vb = vt + ((size_t)(b * NHEAD + h)) * HD * NP;

    s16x8 bq = {0,0,0,0,0,0,0,0};
    {
      s16x4 t4 = *reinterpret_cast<const s16x4*>(qb + n * HD + 4 * g);
      bq[0]=t4[0]; bq[1]=t4[1]; bq[2]=t4[2]; bq[3]=t4[3];
    }
    f32x4 acc[16];
#pragma unroll
    for (int t = 0; t < 16; ++t) {
      s16x8 akf = {0,0,0,0,0,0,0,0};
      s16x4 t4 = *reinterpret_cast<const s16x4*>(kb + (mw * 256 + t * 16 + c) * HD + 4 * g);
      akf[0]=t4[0]; akf[1]=t4[1]; akf[2]=t4[2]; akf[3]=t4[3];
      acc[t] = MFMA(akf, bq, (f32x4){0,0,0,0});
    }
    float lmax = -3e38f;
#pragma unroll
    for (int t = 0; t < 16; ++t) {
      int mb = mw * 256 + t * 16 + 4 * g;
#pragma unroll
      for (int r = 0; r < 4; ++r) {
        float lv = (mb + r < NN_) ? fmaf(acc[t][r], 0.25f, mreg[t][r]) : -3e38f;
        acc[t][r] = lv;
        lmax = fmaxf(lmax, lv);
      }
    }
    lmax = fmaxf(lmax, __shfl_xor(lmax, 16));
    lmax = fmaxf(lmax, __shfl_xor(lmax, 32));
    if (g == 0) redmax[mw][nw][c] = lmax;
    __syncthreads();                      // B1
    float gmax = fmaxf(redmax[0][nw][c], redmax[1][nw][c]);
    float lsum = 0.0f;
#pragma unroll
    for (int t = 0; t < 16; ++t) {
#pragma unroll
      for (int r = 0; r < 4; ++r) {
        float p = exp2f((acc[t][r] - gmax) * 1.4426950408889634f);
        acc[t][r] = p;
        lsum += p;
      }
    }
    lsum += __shfl_xor(lsum, 16);
    lsum += __shfl_xor(lsum, 32);
    if (g == 0) redsum[mw][nw][c] = lsum;

    // PV: out^T = V^T * P ; identical (g,slot) k-placement on both operands
    f32x4 o = {0,0,0,0};
#pragma unroll
    for (int T = 0; T < 8; ++T) {
      int m0 = mw * 256 + T * 32;
      s16x4 va = *reinterpret_cast<const s16x4*>(vb + (size_t)c * NP + m0 + 4 * g);
      s16x4 vb2 = *reinterpret_cast<const s16x4*>(vb + (size_t)c * NP + m0 + 16 + 4 * g);
      s16x8 af = { va[0], va[1], va[2], va[3], vb2[0], vb2[1], vb2[2], vb2[3] };
      s16x8 bfv;
#pragma unroll
      for (int j = 0; j < 4; ++j) {
        bfv[j]     = (short)f2bf(acc[2 * T][j]);
        bfv[j + 4] = (short)f2bf(acc[2 * T + 1][j]);
      }
      o = MFMA(af, bfv, o);
    }
    __syncthreads();                      // B2: redsum visible; prev pvred reads done
    float gsum = redsum[0][nw][c] + redsum[1][nw][c];
#pragma unroll
    for (int r = 0; r < 4; ++r) pvred[mw][nw][4 * g + r][c] = o[r];
    __syncthreads();                      // B3
    if (mw == 0) {
      float inv = 1.0f / gsum;
      s16x4 st;
#pragma unroll
      for (int r = 0; r < 4; ++r) {
        float v = (pvred[0][nw][4 * g + r][c] + pvred[1][nw][4 * g + r][c]) * inv;
        st[r] = (short)f2bf(v);
      }
      *reinterpret_cast<s16x4*>(ao_bf + ((size_t)(b * NP + n)) * EE + h * HD + 4 * g) = st;
    }
  }
}

// ---------------- K3: mh = attn_out @ Wc + bc -> bf16 ----------------
__global__ __launch_bounds__(256) void k_comb(
    const unsigned short* __restrict__ ao_bf, const unsigned short* __restrict__ wt,
    const float* __restrict__ bc, unsigned short* __restrict__ mh_bf) {
  int wgid = blockIdx.x;                 // 1024
  int xcd = wgid & 7;
  int s = wgid >> 3;
  int nt = s & 15;
  int b = (s >> 4) * 8 + xcd;
  int tid = threadIdx.x;
  int w = tid >> 6, lane = tid & 63, g = lane >> 4, c = lane & 15;
  int rw = w & 1, cw = w >> 1;
  int nbase = nt * 32 + rw * 16;
  int nA = nbase + c;
  f32x4 a4[4];
#pragma unroll
  for (int t = 0; t < 4; ++t) a4[t] = (f32x4){0,0,0,0};
  for (int kk = 0; kk < 4; ++kk) {
    int k0 = kk * 32 + 8 * g;
    s16x8 aa = *reinterpret_cast<const s16x8*>(ao_bf + ((size_t)(b * NP + nA)) * EE + k0);
#pragma unroll
    for (int tc = 0; tc < 4; ++tc) {
      int e = cw * 64 + tc * 16 + c;
      s16x8 bw = *reinterpret_cast<const s16x8*>(wt + 4 * 16384 + e * EE + k0);
      a4[tc] = MFMA(aa, bw, a4[tc]);
    }
  }
#pragma unroll
  for (int tc = 0; tc < 4; ++tc) {
    int e = cw * 64 + tc * 16 + c;
    float bias = bc[e];
#pragma unroll
    for (int r = 0; r < 4; ++r) {
      int n = nbase + 4 * g + r;
      mh_bf[((size_t)(b * NP + n)) * EE + e] = f2bf(a4[tc][r] + bias);
    }
  }
}

// ---------------- K4: pointer attention: s = mh@ef^T /sqrt(128); 10*tanh + mask; softmax ----------------
__global__ __launch_bounds__(256) void k_logits(
    const unsigned short* __restrict__ mh_bf, const unsigned short* __restrict__ ef_bf,
    const float* __restrict__ mask, float* __restrict__ probs) {
  int wgid = blockIdx.x;                 // 1024
  int xcd = wgid & 7;
  int sfl = wgid >> 3;
  int nt = sfl & 15;
  int bq = sfl >> 4;                     // 0..7
  int b = bq * 8 + xcd;                  // same-b tiles on same XCD
  int tid = threadIdx.x, w = tid >> 6, lane = tid & 63, g = lane >> 4, c = lane & 15;
  int rw = w & 1, cw = w >> 1;
  int nbase = nt * 32 + rw * 16;
  int nA = nbase + c;

  f32x4 acc[16];
#pragma unroll
  for (int t = 0; t < 16; ++t) acc[t] = (f32x4){0,0,0,0};
  for (int kk = 0; kk < 4; ++kk) {
    int k0 = kk * 32 + 8 * g;
    s16x8 af = *reinterpret_cast<const s16x8*>(mh_bf + ((size_t)(b * NP + nA)) * EE + k0);
#pragma unroll
    for (int t = 0; t < 16; ++t) {
      int m = cw * 256 + t * 16 + c;
      s16x8 bfr = *reinterpret_cast<const s16x8*>(ef_bf + ((size_t)(b * NP + m)) * EE + k0);
      acc[t] = MFMA(af, bfr, acc[t]);
    }
  }
  float rmax[4] = {-3e38f, -3e38f, -3e38f, -3e38f};
#pragma unroll
  for (int t = 0; t < 16; ++t) {
    int m = cw * 256 + t * 16 + c;
#pragma unroll
    for (int r = 0; r < 4; ++r) {
      int n = nbase + 4 * g + r;
      float lv;
      if (m < NN_) {
        float x = acc[t][r] * 0.08838834764831845f;  // 1/sqrt(128)
        float ax = fabsf(x);
        float e2 = exp2f(ax * 2.8853900817779268f);  // e^(2|x|)
        float th = copysignf(1.0f - 2.0f / (e2 + 1.0f), x);
        float mv = (n < NN_) ? mask[((size_t)b * NN_ + n) * NN_ + m] : 0.0f;
        lv = 10.0f * th + mv;
      } else {
        lv = -3e38f;
      }
      acc[t][r] = lv;
      rmax[r] = fmaxf(rmax[r], lv);
    }
  }
#pragma unroll
  for (int r = 0; r < 4; ++r) {
    rmax[r] = fmaxf(rmax[r], __shfl_xor(rmax[r], 1));
    rmax[r] = fmaxf(rmax[r], __shfl_xor(rmax[r], 2));
    rmax[r] = fmaxf(rmax[r], __shfl_xor(rmax[r], 4));
    rmax[r] = fmaxf(rmax[r], __shfl_xor(rmax[r], 8));
  }
  __shared__ float redm[2][32];
  __shared__ float reds[2][32];
  int rowid = rw * 16 + 4 * g;
  if (c == 0) {
#pragma unroll
    for (int r = 0; r < 4; ++r) redm[cw][rowid + r] = rmax[r];
  }
  __syncthreads();
  float gmax[4];
#pragma unroll
  for (int r = 0; r < 4; ++r) gmax[r] = fmaxf(redm[0][rowid + r], redm[1][rowid + r]);
  float rsum[4] = {0, 0, 0, 0};
#pragma unroll
  for (int t = 0; t < 16; ++t) {
#pragma unroll
    for (int r = 0; r < 4; ++r) {
      float p = exp2f((acc[t][r] - gmax[r]) * 1.4426950408889634f);
      acc[t][r] = p;
      rsum[r] += p;
    }
  }
#pragma unroll
  for (int r = 0; r < 4; ++r) {
    rsum[r] += __shfl_xor(rsum[r], 1);
    rsum[r] += __shfl_xor(rsum[r], 2);
    rsum[r] += __shfl_xor(rsum[r], 4);
    rsum[r] += __shfl_xor(rsum[r], 8);
  }
  if (c == 0) {
#pragma unroll
    for (int r = 0; r < 4; ++r) reds[cw][rowid + r] = rsum[r];
  }
  __syncthreads();
  float inv[4];
#pragma unroll
  for (int r = 0; r < 4; ++r) inv[r] = 1.0f / (reds[0][rowid + r] + reds[1][rowid + r]);
#pragma unroll
  for (int t = 0; t < 16; ++t) {
    int m = cw * 256 + t * 16 + c;
    if (m < NN_) {
#pragma unroll
      for (int r = 0; r < 4; ++r) {
        int n = nbase + 4 * g + r;
        if (n < NN_) probs[((size_t)b * NN_ + n) * NN_ + m] = acc[t][r] * inv[r];
      }
    }
  }
}

extern "C" void kernel_launch(void* const* d_in, const int* in_sizes, int n_in,
                              void* d_out, int out_size, void* d_ws, size_t ws_size,
                              hipStream_t stream) {
  const float* ef   = (const float*)d_in[0];
  const float* eq1  = (const float*)d_in[1];
  const float* eq0  = (const float*)d_in[2];
  const float* mask = (const float*)d_in[3];
  const float* wq1  = (const float*)d_in[4];
  const float* wq0  = (const float*)d_in[5];
  const float* wk   = (const float*)d_in[6];
  const float* wv   = (const float*)d_in[7];
  const float* wc   = (const float*)d_in[8];
  const float* bc   = (const float*)d_in[9];
  float* probs = (float*)d_out;

  char* ws = (char*)d_ws;
  const size_t SL = 8388608;  // 64*512*128*2 bytes
  unsigned short* ef_bf = (unsigned short*)(ws);
  unsigned short* qh    = (unsigned short*)(ws + 1 * SL);
  unsigned short* kh    = (unsigned short*)(ws + 2 * SL);
  unsigned short* vt_bf = (unsigned short*)(ws + 3 * SL);
  unsigned short* ao_bf = (unsigned short*)(ws + 4 * SL);
  unsigned short* mh_bf = (unsigned short*)(ws + 5 * SL);
  unsigned short* wt    = (unsigned short*)(ws + 6 * SL);

  k_conv_ef<<<2048, 256, 0, stream>>>(ef, ef_bf);
  k_conv_w<<<320, 256, 0, stream>>>(wq1, wq0, wk, wv, wc, wt);
  k_proj<<<1024, 256, 0, stream>>>(ef_bf, eq1, eq0, wt, qh, kh, vt_bf);
  k_attn<<<1024, 256, 0, stream>>>(qh, kh, vt_bf, mask, ao_bf);
  k_comb<<<1024, 256, 0, stream>>>(ao_bf, wt, bc, mh_bf);
  k_logits<<<1024, 256, 0, stream>>>(mh_bf, ef_bf, mask, probs);
}

// Round 3
// 203.239 us; speedup vs baseline: 2.1987x; 1.5845x over previous
//
#include <hip/hip_runtime.h>
#include <hip/hip_bf16.h>
#include <cstdint>

#define BB 64
#define NN_ 500
#define NP 512
#define EE 128
#define NHEAD 8
#define HD 16

typedef float f32x4 __attribute__((ext_vector_type(4)));
typedef short s16x8 __attribute__((ext_vector_type(8)));
typedef short s16x4 __attribute__((ext_vector_type(4)));

__device__ __forceinline__ unsigned short f2bf(float f) {
  unsigned u = __builtin_bit_cast(unsigned, f);
  u += 0x7FFFu + ((u >> 16) & 1u);
  return (unsigned short)(u >> 16);
}

__device__ __forceinline__ float bf2f(unsigned short u) {
  unsigned v = ((unsigned)u) << 16;
  return __builtin_bit_cast(float, v);
}

__device__ __forceinline__ f32x4 MFMA(s16x8 a, s16x8 b, f32x4 c) {
  return __builtin_amdgcn_mfma_f32_16x16x32_bf16(a, b, c, 0, 0, 0);
}

// ---------------- K0a: ef fp32 -> bf16, padded rows 500..511 = 0 ----------------
__global__ void k_conv_ef(const float* __restrict__ ef, unsigned short* __restrict__ out) {
  int idx = blockIdx.x * 256 + threadIdx.x;   // B*NP*16 = 524288
  int e8 = idx & 15;
  int n  = (idx >> 4) & (NP - 1);
  int b  = idx >> 13;
  s16x8 o = {0,0,0,0,0,0,0,0};
  if (n < NN_) {
    const float* p = ef + ((size_t)(b * NN_ + n)) * EE + e8 * 8;
    float4 f0 = *reinterpret_cast<const float4*>(p);
    float4 f1 = *reinterpret_cast<const float4*>(p + 4);
    o[0]=(short)f2bf(f0.x); o[1]=(short)f2bf(f0.y); o[2]=(short)f2bf(f0.z); o[3]=(short)f2bf(f0.w);
    o[4]=(short)f2bf(f1.x); o[5]=(short)f2bf(f1.y); o[6]=(short)f2bf(f1.z); o[7]=(short)f2bf(f1.w);
  }
  *reinterpret_cast<s16x8*>(out + ((size_t)(b * NP + n)) * EE + e8 * 8) = o;
}

// ---------------- K0b: W^T bf16; mats order [q1,q0,k,v,c], WT[m][n][k]=W[k][n] ----------------
__global__ void k_conv_w(const float* __restrict__ w0, const float* __restrict__ w1,
                         const float* __restrict__ w2, const float* __restrict__ w3,
                         const float* __restrict__ w4, unsigned short* __restrict__ wt) {
  int idx = blockIdx.x * 256 + threadIdx.x;   // 5*128*128 = 81920
  int k = idx & 127;
  int n = (idx >> 7) & 127;
  int m = idx >> 14;
  const float* w = (m == 0) ? w0 : (m == 1) ? w1 : (m == 2) ? w2 : (m == 3) ? w3 : w4;
  wt[idx] = f2bf(w[k * 128 + n]);
}

// ---------------- K1: projections -> QH, KH head-major [b][h][n][16], VT [b][h][16][n] ----------------
__global__ __launch_bounds__(256) void k_proj(
    const unsigned short* __restrict__ ef_bf,
    const float* __restrict__ eq1, const float* __restrict__ eq0,
    const unsigned short* __restrict__ wt,
    unsigned short* __restrict__ qh, unsigned short* __restrict__ kh,
    unsigned short* __restrict__ vt_bf) {
  int wgid = blockIdx.x;                 // 1024
  int xcd = wgid & 7;
  int s = wgid >> 3;
  int nt = s & 15;
  int b = (s >> 4) * 8 + xcd;
  int tid = threadIdx.x;
  int w = tid >> 6, lane = tid & 63, g = lane >> 4, c = lane & 15;
  int rw = w & 1, cw = w >> 1;
  int nbase = nt * 32 + rw * 16;

  f32x4 ak[4], av[4], aq[4];
#pragma unroll
  for (int t = 0; t < 4; ++t) { ak[t]=(f32x4){0,0,0,0}; av[t]=(f32x4){0,0,0,0}; aq[t]=(f32x4){0,0,0,0}; }

  int nA = nbase + c;
  int nc = nA < NN_ ? nA : NN_ - 1;

  for (int kk = 0; kk < 4; ++kk) {
    int k0 = kk * 32 + 8 * g;
    s16x8 aef = *reinterpret_cast<const s16x8*>(ef_bf + ((size_t)(b * NP + nA)) * EE + k0);
    const float* p1 = eq1 + ((size_t)(b * NN_ + nc)) * EE + k0;
    const float* p0 = eq0 + ((size_t)(b * NN_ + nc)) * EE + k0;
    float4 u1 = *reinterpret_cast<const float4*>(p1);
    float4 u2 = *reinterpret_cast<const float4*>(p1 + 4);
    float4 v1 = *reinterpret_cast<const float4*>(p0);
    float4 v2 = *reinterpret_cast<const float4*>(p0 + 4);
    s16x8 a1, a0;
    a1[0]=(short)f2bf(u1.x); a1[1]=(short)f2bf(u1.y); a1[2]=(short)f2bf(u1.z); a1[3]=(short)f2bf(u1.w);
    a1[4]=(short)f2bf(u2.x); a1[5]=(short)f2bf(u2.y); a1[6]=(short)f2bf(u2.z); a1[7]=(short)f2bf(u2.w);
    a0[0]=(short)f2bf(v1.x); a0[1]=(short)f2bf(v1.y); a0[2]=(short)f2bf(v1.z); a0[3]=(short)f2bf(v1.w);
    a0[4]=(short)f2bf(v2.x); a0[5]=(short)f2bf(v2.y); a0[6]=(short)f2bf(v2.z); a0[7]=(short)f2bf(v2.w);
#pragma unroll
    for (int tc = 0; tc < 4; ++tc) {
      int e = cw * 64 + tc * 16 + c;
      const unsigned short* wrow = wt + e * EE + k0;
      s16x8 bq1 = *reinterpret_cast<const s16x8*>(wrow);
      s16x8 bq0 = *reinterpret_cast<const s16x8*>(wrow + 1 * 16384);
      s16x8 bk  = *reinterpret_cast<const s16x8*>(wrow + 2 * 16384);
      s16x8 bv  = *reinterpret_cast<const s16x8*>(wrow + 3 * 16384);
      ak[tc] = MFMA(aef, bk, ak[tc]);
      av[tc] = MFMA(aef, bv, av[tc]);
      aq[tc] = MFMA(a1, bq1, aq[tc]);
      aq[tc] = MFMA(a0, bq0, aq[tc]);
    }
  }
#pragma unroll
  for (int tc = 0; tc < 4; ++tc) {
    int h = cw * 4 + tc;                 // e = cw*64+tc*16+c -> head, d = c
    s16x4 pv4;
#pragma unroll
    for (int r = 0; r < 4; ++r) {
      int n = nbase + 4 * g + r;
      bool val = (n < NN_);
      size_t off = ((size_t)((b * NHEAD + h) * NP) + n) * HD + c;
      kh[off] = val ? f2bf(ak[tc][r]) : 0;
      qh[off] = val ? f2bf(aq[tc][r]) : 0;
      pv4[r] = val ? (short)f2bf(av[tc][r]) : (short)0;
    }
    int n0 = nbase + 4 * g;
    *reinterpret_cast<s16x4*>(vt_bf + (((size_t)(b * NHEAD + h)) * HD + c) * NP + n0) = pv4;
  }
}

// ---------------- K2: FUSED attn(8 heads) + combine + pointer-logits per (b, 32-row tile) ----------------
// 512 threads = 8 waves: mw = w&3 (m-split 4-way), nw = w>>2 (n-split 2-way).
// Attn swapped orientation: S^T = mfma(K, Q); softmax over m lane-local + shfl(g) + LDS(mw).
// Mask staged once as bf16, reused for attn softmax and pointer softmax.
// ao tile -> LDS (sao), comb GEMM from LDS, mh written back into sao (aliased), logits GEMM from LDS.
__global__ __launch_bounds__(512) void k_fused(
    const unsigned short* __restrict__ qh, const unsigned short* __restrict__ kh,
    const unsigned short* __restrict__ vt, const unsigned short* __restrict__ ef_bf,
    const unsigned short* __restrict__ wt, const float* __restrict__ bcp,
    const float* __restrict__ mask, float* __restrict__ probs) {
  int wgid = blockIdx.x;                 // 1024
  int xcd = wgid & 7;
  int s = wgid >> 3;
  int nt = s & 15;
  int b = (s >> 4) * 8 + xcd;            // all 16 tiles of b on one XCD
  int tid = threadIdx.x;
  int w = tid >> 6, lane = tid & 63, g = lane >> 4, c = lane & 15;
  int mw = w & 3, nw = w >> 2;
  int nl = nw * 16 + c;                  // attn-phase local n (0..31)
  int nglob = nt * 32 + nl;

  __shared__ unsigned short smask[32][516];   // 33024 B, bf16 mask tile
  __shared__ unsigned short sao[32][132];     // 8448 B, ao tile then mh tile (aliased)
  __shared__ float pvred[4][2][16][17];       // 8704 B
  __shared__ float redm[4][2][16];            // 512 B
  __shared__ float reds[4][2][16];            // 512 B   -> total 51.2 KB -> 3 blocks/CU

  // ---- stage mask tile (bf16), coalesced; rows n>=500 and cols 500..515 zero ----
  smask[tid >> 4][500 + (tid & 15)] = 0;
  for (int idx = tid; idx < 32 * 125; idx += 512) {
    int rl = idx / 125;
    int m4 = idx - rl * 125;
    int nr = nt * 32 + rl;
    float4 v = {0.f, 0.f, 0.f, 0.f};
    if (nr < NN_) v = *reinterpret_cast<const float4*>(mask + ((size_t)b * NN_ + nr) * NN_ + m4 * 4);
    s16x4 pk = { (short)f2bf(v.x), (short)f2bf(v.y), (short)f2bf(v.z), (short)f2bf(v.w) };
    *reinterpret_cast<s16x4*>(&smask[rl][m4 * 4]) = pk;
  }
  __syncthreads();

  // this lane's 32 attn-mask values -> f32 regs (reused across all 8 heads)
  f32x4 mreg[8];
#pragma unroll
  for (int t = 0; t < 8; ++t) {
    s16x4 mm = *reinterpret_cast<const s16x4*>(&smask[nl][mw * 128 + t * 16 + 4 * g]);
#pragma unroll
    for (int j = 0; j < 4; ++j) mreg[t][j] = bf2f((unsigned short)mm[j]);
  }

  // ================= Phase A: attention, 8 heads =================
  for (int h = 0; h < NHEAD; ++h) {
    const unsigned short* qb = qh + ((size_t)(b * NHEAD + h)) * NP * HD;
    const unsigned short* kb = kh + ((size_t)(b * NHEAD + h)) * NP * HD;
    const unsigned short* vb = vt + ((size_t)(b * NHEAD + h)) * HD * NP;

    s16x8 bq = {0,0,0,0,0,0,0,0};
    {
      s16x4 t4 = *reinterpret_cast<const s16x4*>(qb + nglob * HD + 4 * g);
      bq[0]=t4[0]; bq[1]=t4[1]; bq[2]=t4[2]; bq[3]=t4[3];
    }
    f32x4 ac[8];
#pragma unroll
    for (int t = 0; t < 8; ++t) {
      s16x8 akf = {0,0,0,0,0,0,0,0};
      s16x4 k4 = *reinterpret_cast<const s16x4*>(kb + (mw * 128 + t * 16 + c) * HD + 4 * g);
      akf[0]=k4[0]; akf[1]=k4[1]; akf[2]=k4[2]; akf[3]=k4[3];
      ac[t] = MFMA(akf, bq, (f32x4){0,0,0,0});
    }
    float lmax = -3e38f;
#pragma unroll
    for (int t = 0; t < 8; ++t) {
      int mb = mw * 128 + t * 16 + 4 * g;
#pragma unroll
      for (int r = 0; r < 4; ++r) {
        float lv = (mb + r < NN_) ? fmaf(ac[t][r], 0.25f, mreg[t][r]) : -3e38f;
        ac[t][r] = lv;
        lmax = fmaxf(lmax, lv);
      }
    }
    lmax = fmaxf(lmax, __shfl_xor(lmax, 16));
    lmax = fmaxf(lmax, __shfl_xor(lmax, 32));
    if (g == 0) redm[mw][nw][c] = lmax;
    __syncthreads();                      // B1
    float gmax = fmaxf(fmaxf(redm[0][nw][c], redm[1][nw][c]),
                       fmaxf(redm[2][nw][c], redm[3][nw][c]));
    float lsum = 0.0f;
#pragma unroll
    for (int t = 0; t < 8; ++t) {
#pragma unroll
      for (int r = 0; r < 4; ++r) {
        float p = exp2f((ac[t][r] - gmax) * 1.4426950408889634f);
        ac[t][r] = p;
        lsum += p;
      }
    }
    lsum += __shfl_xor(lsum, 16);
    lsum += __shfl_xor(lsum, 32);
    if (g == 0) reds[mw][nw][c] = lsum;

    // PV: out^T = V^T * P ; identical (g,slot) k-placement on both operands
    f32x4 o = {0,0,0,0};
#pragma unroll
    for (int T = 0; T < 4; ++T) {
      int m0 = mw * 128 + T * 32;
      s16x4 va = *reinterpret_cast<const s16x4*>(vb + (size_t)c * NP + m0 + 4 * g);
      s16x4 v2 = *reinterpret_cast<const s16x4*>(vb + (size_t)c * NP + m0 + 16 + 4 * g);
      s16x8 af = { va[0], va[1], va[2], va[3], v2[0], v2[1], v2[2], v2[3] };
      s16x8 pb;
#pragma unroll
      for (int j = 0; j < 4; ++j) {
        pb[j]     = (short)f2bf(ac[2 * T][j]);
        pb[j + 4] = (short)f2bf(ac[2 * T + 1][j]);
      }
      o = MFMA(af, pb, o);
    }
    __syncthreads();                      // B2: reds visible; prev pvred reads done
    float gsum = reds[0][nw][c] + reds[1][nw][c] + reds[2][nw][c] + reds[3][nw][c];
#pragma unroll
    for (int r = 0; r < 4; ++r) pvred[mw][nw][4 * g + r][c] = o[r];
    __syncthreads();                      // B3
    if (mw == 0) {
      float inv = 1.0f / gsum;
#pragma unroll
      for (int r = 0; r < 4; ++r) {
        int dd = 4 * g + r;
        float v = (pvred[0][nw][dd][c] + pvred[1][nw][dd][c] +
                   pvred[2][nw][dd][c] + pvred[3][nw][dd][c]) * inv;
        sao[nl][h * 16 + dd] = f2bf(v);
      }
    }
  }
  __syncthreads();                        // B4: sao (ao tile) complete

  // ================= Phase B: mh = ao @ Wc + bc =================
  float bias0 = bcp[mw * 32 + c];
  float bias1 = bcp[mw * 32 + 16 + c];
  f32x4 acm0 = {0,0,0,0}, acm1 = {0,0,0,0};
#pragma unroll
  for (int kk = 0; kk < 4; ++kk) {
    int k0 = kk * 32 + 8 * g;
    s16x8 aa = *reinterpret_cast<const s16x8*>(&sao[nw * 16 + c][k0]);
    s16x8 bw0 = *reinterpret_cast<const s16x8*>(wt + 4 * 16384 + (mw * 32 + c) * EE + k0);
    s16x8 bw1 = *reinterpret_cast<const s16x8*>(wt + 4 * 16384 + (mw * 32 + 16 + c) * EE + k0);
    acm0 = MFMA(aa, bw0, acm0);
    acm1 = MFMA(aa, bw1, acm1);
  }
  __syncthreads();                        // B5: all sao reads done
#pragma unroll
  for (int r = 0; r < 4; ++r) {
    sao[nw * 16 + 4 * g + r][mw * 32 + c]      = f2bf(acm0[r] + bias0);
    sao[nw * 16 + 4 * g + r][mw * 32 + 16 + c] = f2bf(acm1[r] + bias1);
  }
  __syncthreads();                        // B6: mh tile ready

  // ================= Phase C: pointer logits + softmax =================
  s16x8 am[4];
#pragma unroll
  for (int kk = 0; kk < 4; ++kk)
    am[kk] = *reinterpret_cast<const s16x8*>(&sao[nw * 16 + c][kk * 32 + 8 * g]);
  f32x4 sc[8];
#pragma unroll
  for (int t = 0; t < 8; ++t) sc[t] = (f32x4){0,0,0,0};
#pragma unroll
  for (int kk = 0; kk < 4; ++kk) {
    int k0 = kk * 32 + 8 * g;
#pragma unroll
    for (int t = 0; t < 8; ++t) {
      int m = mw * 128 + t * 16 + c;
      s16x8 bfr = *reinterpret_cast<const s16x8*>(ef_bf + ((size_t)(b * NP + m)) * EE + k0);
      sc[t] = MFMA(am[kk], bfr, sc[t]);
    }
  }
  float rmax[4] = {-3e38f, -3e38f, -3e38f, -3e38f};
#pragma unroll
  for (int t = 0; t < 8; ++t) {
    int m = mw * 128 + t * 16 + c;
    bool mv = (m < NN_);
#pragma unroll
    for (int r = 0; r < 4; ++r) {
      float lv = -3e38f;
      if (mv) {
        float x = sc[t][r] * 0.08838834764831845f;  // 1/sqrt(128)
        float ax = fabsf(x);
        float e2 = exp2f(ax * 2.8853900817779268f); // e^(2|x|)
        float th = copysignf(1.0f - 2.0f / (e2 + 1.0f), x);
        lv = fmaf(th, 10.0f, bf2f(smask[nw * 16 + 4 * g + r][m]));
      }
      sc[t][r] = lv;
      rmax[r] = fmaxf(rmax[r], lv);
    }
  }
#pragma unroll
  for (int r = 0; r < 4; ++r) {
    rmax[r] = fmaxf(rmax[r], __shfl_xor(rmax[r], 1));
    rmax[r] = fmaxf(rmax[r], __shfl_xor(rmax[r], 2));
    rmax[r] = fmaxf(rmax[r], __shfl_xor(rmax[r], 4));
    rmax[r] = fmaxf(rmax[r], __shfl_xor(rmax[r], 8));
  }
  if (c == 0) {
#pragma unroll
    for (int r = 0; r < 4; ++r) redm[mw][nw][4 * g + r] = rmax[r];
  }
  __syncthreads();                        // C1
  float gmax2[4];
#pragma unroll
  for (int r = 0; r < 4; ++r) {
    int rr = 4 * g + r;
    gmax2[r] = fmaxf(fmaxf(redm[0][nw][rr], redm[1][nw][rr]),
                     fmaxf(redm[2][nw][rr], redm[3][nw][rr]));
  }
  float rsum[4] = {0, 0, 0, 0};
#pragma unroll
  for (int t = 0; t < 8; ++t) {
#pragma unroll
    for (int r = 0; r < 4; ++r) {
      float p = exp2f((sc[t][r] - gmax2[r]) * 1.4426950408889634f);
      sc[t][r] = p;
      rsum[r] += p;
    }
  }
#pragma unroll
  for (int r = 0; r < 4; ++r) {
    rsum[r] += __shfl_xor(rsum[r], 1);
    rsum[r] += __shfl_xor(rsum[r], 2);
    rsum[r] += __shfl_xor(rsum[r], 4);
    rsum[r] += __shfl_xor(rsum[r], 8);
  }
  if (c == 0) {
#pragma unroll
    for (int r = 0; r < 4; ++r) reds[mw][nw][4 * g + r] = rsum[r];
  }
  __syncthreads();                        // C2
  float inv[4];
#pragma unroll
  for (int r = 0; r < 4; ++r) {
    int rr = 4 * g + r;
    inv[r] = 1.0f / (reds[0][nw][rr] + reds[1][nw][rr] + reds[2][nw][rr] + reds[3][nw][rr]);
  }
#pragma unroll
  for (int t = 0; t < 8; ++t) {
    int m = mw * 128 + t * 16 + c;
    if (m < NN_) {
#pragma unroll
      for (int r = 0; r < 4; ++r) {
        int ng = nt * 32 + nw * 16 + 4 * g + r;
        if (ng < NN_) probs[((size_t)b * NN_ + ng) * NN_ + m] = sc[t][r] * inv[r];
      }
    }
  }
}

extern "C" void kernel_launch(void* const* d_in, const int* in_sizes, int n_in,
                              void* d_out, int out_size, void* d_ws, size_t ws_size,
                              hipStream_t stream) {
  const float* ef   = (const float*)d_in[0];
  const float* eq1  = (const float*)d_in[1];
  const float* eq0  = (const float*)d_in[2];
  const float* mask = (const float*)d_in[3];
  const float* wq1  = (const float*)d_in[4];
  const float* wq0  = (const float*)d_in[5];
  const float* wk   = (const float*)d_in[6];
  const float* wv   = (const float*)d_in[7];
  const float* wc   = (const float*)d_in[8];
  const float* bc   = (const float*)d_in[9];
  float* probs = (float*)d_out;

  char* ws = (char*)d_ws;
  const size_t SL = 8388608;  // 64*512*128*2 bytes
  unsigned short* ef_bf = (unsigned short*)(ws);
  unsigned short* qh    = (unsigned short*)(ws + 1 * SL);
  unsigned short* kh    = (unsigned short*)(ws + 2 * SL);
  unsigned short* vt_bf = (unsigned short*)(ws + 3 * SL);
  unsigned short* wt    = (unsigned short*)(ws + 4 * SL);

  k_conv_ef<<<2048, 256, 0, stream>>>(ef, ef_bf);
  k_conv_w<<<320, 256, 0, stream>>>(wq1, wq0, wk, wv, wc, wt);
  k_proj<<<1024, 256, 0, stream>>>(ef_bf, eq1, eq0, wt, qh, kh, vt_bf);
  k_fused<<<1024, 512, 0, stream>>>(qh, kh, vt_bf, ef_bf, wt, bc, mask, probs);
}